// Round 4
// baseline (263.163 us; speedup 1.0000x reference)
//
#include <hip/hip_runtime.h>
#include <hip/hip_cooperative_groups.h>

#define BATCH 4
#define SEQ   4096
#define EMB   512
#define HD    64

namespace cg = cooperative_groups;

typedef __attribute__((ext_vector_type(8))) short short8;
typedef __attribute__((ext_vector_type(4))) float floatx4;

static __device__ __forceinline__ unsigned short f2bf(float f) {
  unsigned u = __builtin_bit_cast(unsigned, f);
  u += 0x7fffu + ((u >> 16) & 1u);           // round-to-nearest-even
  return (unsigned short)(u >> 16);
}
static __device__ __forceinline__ float bf2f(unsigned short h) {
  unsigned u = ((unsigned)h) << 16;
  return __builtin_bit_cast(float, u);
}
static __device__ __forceinline__ unsigned pack_hi16(float lo, float hi) {
#if __has_builtin(__builtin_amdgcn_perm)
  return __builtin_amdgcn_perm(__builtin_bit_cast(unsigned, hi),
                               __builtin_bit_cast(unsigned, lo), 0x07060302u);
#else
  return (__builtin_bit_cast(unsigned, lo) >> 16) |
         (__builtin_bit_cast(unsigned, hi) & 0xffff0000u);
#endif
}
static __device__ __forceinline__ unsigned pack_f16(float a, float b) {
#if __has_builtin(__builtin_amdgcn_cvt_pkrtz)
  typedef __fp16 fp16v2 __attribute__((ext_vector_type(2)));
  fp16v2 h = __builtin_amdgcn_cvt_pkrtz(a, b);
  return __builtin_bit_cast(unsigned, h);
#else
  _Float16 ha = (_Float16)a, hb = (_Float16)b;
  return (unsigned)__builtin_bit_cast(unsigned short, ha) |
         ((unsigned)__builtin_bit_cast(unsigned short, hb) << 16);
#endif
}
static __device__ __forceinline__ float f16_to_f32(unsigned short bits) {
  _Float16 h = __builtin_bit_cast(_Float16, bits);
  return (float)h;
}

// ---------------------------------------------------------------------------
// Kernel 0: pack W into MFMA fragment order, bf16. (unchanged, verified)
// ---------------------------------------------------------------------------
__global__ __launch_bounds__(256) void convw_kernel(
    const float* __restrict__ WQ, const float* __restrict__ WK,
    const float* __restrict__ WV, unsigned short* __restrict__ Wpk)
{
  int t = blockIdx.x * 256 + threadIdx.x;     // 0..16383
  int p    = t >> 12;
  int w    = (t >> 10) & 3;
  int kc   = (t >> 6) & 15;
  int lane = t & 63;
  int lr = lane & 15, g = lane >> 4;
  const float* src = (p == 0) ? WQ : ((p == 1) ? WK : WV);
  const float4* s4 = (const float4*)(src + (16 * w + lr) * EMB + kc * 32 + 8 * g);
  float4 a = s4[0], b = s4[1];
  float vv[8] = {a.x, a.y, a.z, a.w, b.x, b.y, b.z, b.w};
  short8 o;
#pragma unroll
  for (int j = 0; j < 8; ++j) {
    unsigned short h = f2bf(vv[j]);
    o[j] = (p == 3) ? (short)f2bf(vv[j] - bf2f(h)) : (short)h;
  }
  *(short8*)(Wpk + (size_t)t * 8) = o;
}

#define XST 40   // proj LDS x row stride in shorts
#define PST 72   // flash P row stride in shorts

// ---------------------------------------------------------------------------
// MEGA kernel (cooperative): proj -> grid.sync -> flash -> grid.sync ->
// combine. Same math as the verified R1 three-kernel path; grid.sync()
// (runtime-blessed barrier) provides cross-XCD visibility instead of the
// hand-rolled fence protocol that failed in R2/R3.
// LDS: one 69.6 KB buffer unioned across phases -> 2 blocks/CU, 512 blocks
// co-resident (cooperative capacity OK).
// ---------------------------------------------------------------------------
__global__ __launch_bounds__(256, 2) void mega_kernel(
    const float* __restrict__ x,
    const unsigned short* __restrict__ Wpk,
    unsigned short* __restrict__ Qb,
    unsigned short* __restrict__ Kb,
    unsigned short* __restrict__ VTb,
    unsigned short* __restrict__ Opart,   // fp16 bits [64*8][256][64]
    float* __restrict__ Lpart,            // [64*8][256]
    float* __restrict__ out)              // [16384][64] f32 final
{
  __shared__ __align__(16) unsigned short SM[34816];   // 69632 B

  cg::grid_group grid = cg::this_grid();

  const int tid  = threadIdx.x;
  const int lane = tid & 63;
  const int w    = tid >> 6;
  const int lr   = lane & 15, g = lane >> 4;

  // ======================= Phase 1: QKV projection =======================
  {
    unsigned short* Xh = SM;              // [2][32*XST] = 2560 shorts
    unsigned short* Xl = SM + 2560;       // [2][32*XST]
    const long rowBase = (long)blockIdx.x * 32;

    floatx4 accQ[2], accK[2], accV[2];
#pragma unroll
    for (int rt = 0; rt < 2; ++rt) {
      floatx4 z = {0.f, 0.f, 0.f, 0.f};
      accQ[rt] = z; accK[rt] = z; accV[rt] = z;
    }

    const int srow = tid >> 3;          // 0..31
    const int sc   = 4 * (tid & 7);     // 0,4,..,28
    const float* xbase = x + (rowBase + srow) * EMB + sc;

    auto stage_write = [&](float4 v, int buf) {
      float vv[4] = {v.x, v.y, v.z, v.w};
      ushort4 hi, lo;
#pragma unroll
      for (int i = 0; i < 4; ++i) {
        unsigned short h = f2bf(vv[i]);
        ((unsigned short*)&hi)[i] = h;
        ((unsigned short*)&lo)[i] = f2bf(vv[i] - bf2f(h));
      }
      *(ushort4*)&Xh[buf * 1280 + srow * XST + sc] = hi;
      *(ushort4*)&Xl[buf * 1280 + srow * XST + sc] = lo;
    };

    short8 Wb[2][4];
    {
      const unsigned short* wb_ = Wpk + (size_t)(w * 16) * 512 + lane * 8;
      Wb[0][0] = *(const short8*)(wb_);
      Wb[0][1] = *(const short8*)(wb_ + 32768);
      Wb[0][2] = *(const short8*)(wb_ + 2 * 32768);
      Wb[0][3] = *(const short8*)(wb_ + 3 * 32768);
    }

    float4 xv = *(const float4*)(xbase);          // kc=0
    stage_write(xv, 0);
    float4 xn1 = *(const float4*)(xbase + 32);    // kc=1
    float4 xn2 = *(const float4*)(xbase + 64);    // kc=2
    float4 xn3 = *(const float4*)(xbase + 96);    // kc=3

#pragma unroll 2
    for (int kc = 0; kc < 16; ++kc) {
      if (kc + 1 < 16) {
        const unsigned short* wb_ = Wpk + (size_t)(w * 16 + kc + 1) * 512 + lane * 8;
        Wb[(kc + 1) & 1][0] = *(const short8*)(wb_);
        Wb[(kc + 1) & 1][1] = *(const short8*)(wb_ + 32768);
        Wb[(kc + 1) & 1][2] = *(const short8*)(wb_ + 2 * 32768);
        Wb[(kc + 1) & 1][3] = *(const short8*)(wb_ + 3 * 32768);
      }
      float4 xfut;
      if (kc + 4 < 16) xfut = *(const float4*)(xbase + (kc + 4) * 32);
      __syncthreads();
      const int buf = kc & 1;
#pragma unroll
      for (int rt = 0; rt < 2; ++rt) {
        short8 xh = *(const short8*)&Xh[buf * 1280 + (16 * rt + lr) * XST + 8 * g];
        short8 xl = *(const short8*)&Xl[buf * 1280 + (16 * rt + lr) * XST + 8 * g];
        accQ[rt] = __builtin_amdgcn_mfma_f32_16x16x32_bf16(Wb[buf][0], xh, accQ[rt], 0, 0, 0);
        accK[rt] = __builtin_amdgcn_mfma_f32_16x16x32_bf16(Wb[buf][1], xh, accK[rt], 0, 0, 0);
        accV[rt] = __builtin_amdgcn_mfma_f32_16x16x32_bf16(xh, Wb[buf][2], accV[rt], 0, 0, 0);
        accV[rt] = __builtin_amdgcn_mfma_f32_16x16x32_bf16(xl, Wb[buf][2], accV[rt], 0, 0, 0);
        accV[rt] = __builtin_amdgcn_mfma_f32_16x16x32_bf16(xh, Wb[buf][3], accV[rt], 0, 0, 0);
      }
      if (kc + 1 < 16) { stage_write(xn1, (kc + 1) & 1); xn1 = xn2; xn2 = xn3; xn3 = xfut; }
    }

    const int bb  = (int)(rowBase >> 12);
    const int sIn = (int)(rowBase & 4095);
#pragma unroll
    for (int rt = 0; rt < 2; ++rt) {
      {
        long row = rowBase + 16 * rt + lr;
        int  col = 16 * w + 4 * g;
        ushort4 u; u.x = f2bf(accQ[rt][0]); u.y = f2bf(accQ[rt][1]);
        u.z = f2bf(accQ[rt][2]); u.w = f2bf(accQ[rt][3]);
        *(ushort4*)(Qb + row * HD + col) = u;
        ushort4 v; v.x = f2bf(accK[rt][0]); v.y = f2bf(accK[rt][1]);
        v.z = f2bf(accK[rt][2]); v.w = f2bf(accK[rt][3]);
        *(ushort4*)(Kb + row * HD + col) = v;
      }
      {
        long addr = ((long)(bb * 64 + 16 * w + lr)) * SEQ + sIn + 16 * rt + 4 * g;
        ushort4 u; u.x = f2bf(accV[rt][0]); u.y = f2bf(accV[rt][1]);
        u.z = f2bf(accV[rt][2]); u.w = f2bf(accV[rt][3]);
        *(ushort4*)(VTb + addr) = u;
      }
    }
  }

  grid.sync();   // Qb/Kb/VTb visible grid-wide

  // ======================= Phase 2: flash partials =======================
  {
    unsigned short* K0 = SM;               // 4096 shorts
    unsigned short* V0 = SM + 4096;
    unsigned short* K1 = SM + 8192;
    unsigned short* V1 = SM + 12288;
    unsigned short* Pw = SM + 16384 + w * (64 * PST);   // this wave's P rows

    const int qb   = blockIdx.x >> 3;
    const int ks   = blockIdx.x & 7;
    const int bb   = qb >> 4;
    const long qrow0 = (long)qb * 256 + 64 * w;
    const int  kbase = ks * 512;

    short8 qf[4][2];
#pragma unroll
    for (int qh = 0; qh < 4; ++qh)
#pragma unroll
      for (int ec = 0; ec < 2; ++ec)
        qf[qh][ec] = *(const short8*)(Qb + (qrow0 + 16 * qh + lr) * HD + ec * 32 + 8 * g);

    floatx4 accO[4][4];
    floatx4 accL[4];
#pragma unroll
    for (int qh = 0; qh < 4; ++qh) {
      floatx4 z = {0.f, 0.f, 0.f, 0.f};
#pragma unroll
      for (int t = 0; t < 4; ++t) accO[qh][t] = z;
      accL[qh] = z;
    }
    short8 onesf;
#pragma unroll
    for (int j = 0; j < 8; ++j) onesf[j] = (short)0x3F80;

    const float cp = 0.18033688011112042f;   // (1/sqrt(64)) * log2(e)
    const float SH = 2.0f;

#define STAGE(kt_, KL, VL) do {                                               \
    const int k0_ = kbase + (kt_) * 64;                                       \
    _Pragma("unroll")                                                         \
    for (int h_ = 0; h_ < 2; ++h_) {                                          \
      int ci_  = h_ * 256 + tid;                                              \
      int row_ = ci_ >> 3;                                                    \
      int cc_  = (ci_ & 7) ^ (row_ & 7);                                      \
      const unsigned short* gK_ = Kb + ((long)bb * SEQ + k0_ + row_) * HD + cc_ * 8; \
      __builtin_amdgcn_global_load_lds(                                       \
          (const __attribute__((address_space(1))) void*)gK_,                 \
          (__attribute__((address_space(3))) void*)((KL) + ci_ * 8), 16, 0, 0); \
      const unsigned short* gV_ = VTb + ((long)bb * HD + row_) * SEQ + k0_ + cc_ * 8; \
      __builtin_amdgcn_global_load_lds(                                       \
          (const __attribute__((address_space(1))) void*)gV_,                 \
          (__attribute__((address_space(3))) void*)((VL) + ci_ * 8), 16, 0, 0); \
    }                                                                         \
  } while (0)

#define COMPUTE(KL, VL) do {                                                  \
    short8 kf[2][4];                                                          \
    _Pragma("unroll")                                                         \
    for (int ec = 0; ec < 2; ++ec)                                            \
      _Pragma("unroll")                                                       \
      for (int t = 0; t < 4; ++t) {                                           \
        int key  = 16 * t + lr;                                               \
        int slot = key * 8 + ((4 * ec + g) ^ (key & 7));                      \
        kf[ec][t] = *(const short8*)((KL) + slot * 8);                        \
      }                                                                       \
    _Pragma("unroll")                                                         \
    for (int qh = 0; qh < 4; ++qh) {                                          \
      floatx4 s_[4];                                                          \
      _Pragma("unroll")                                                       \
      for (int t = 0; t < 4; ++t) { floatx4 z = {0.f,0.f,0.f,0.f}; s_[t] = z; } \
      _Pragma("unroll")                                                       \
      for (int ec = 0; ec < 2; ++ec)                                          \
        _Pragma("unroll")                                                     \
        for (int t = 0; t < 4; ++t)                                           \
          s_[t] = __builtin_amdgcn_mfma_f32_16x16x32_bf16(kf[ec][t], qf[qh][ec], s_[t], 0, 0, 0); \
      unsigned short* prow = Pw + (16 * qh + lr) * PST;                       \
      _Pragma("unroll")                                                       \
      for (int t = 0; t < 4; ++t) {                                           \
        float p0 = __builtin_amdgcn_exp2f(__builtin_fmaf(s_[t][0], cp, -SH)); \
        float p1 = __builtin_amdgcn_exp2f(__builtin_fmaf(s_[t][1], cp, -SH)); \
        float p2 = __builtin_amdgcn_exp2f(__builtin_fmaf(s_[t][2], cp, -SH)); \
        float p3 = __builtin_amdgcn_exp2f(__builtin_fmaf(s_[t][3], cp, -SH)); \
        uint2 u;                                                              \
        u.x = pack_hi16(p0, p1);                                              \
        u.y = pack_hi16(p2, p3);                                              \
        *(uint2*)(prow + 16 * t + 4 * g) = u;                                 \
      }                                                                       \
    }                                                                         \
    short8 vf[2][4];                                                          \
    _Pragma("unroll")                                                         \
    for (int c = 0; c < 2; ++c)                                               \
      _Pragma("unroll")                                                       \
      for (int t = 0; t < 4; ++t) {                                           \
        int d    = 16 * t + lr;                                               \
        int slot = d * 8 + ((4 * c + g) ^ (d & 7));                           \
        vf[c][t] = *(const short8*)((VL) + slot * 8);                         \
      }                                                                       \
    _Pragma("unroll")                                                         \
    for (int qh = 0; qh < 4; ++qh)                                            \
      _Pragma("unroll")                                                       \
      for (int c = 0; c < 2; ++c) {                                           \
        short8 pf = *(const short8*)(Pw + (16 * qh + lr) * PST + 32 * c + 8 * g); \
        _Pragma("unroll")                                                     \
        for (int t = 0; t < 4; ++t)                                           \
          accO[qh][t] = __builtin_amdgcn_mfma_f32_16x16x32_bf16(vf[c][t], pf, accO[qh][t], 0, 0, 0); \
        accL[qh] = __builtin_amdgcn_mfma_f32_16x16x32_bf16(onesf, pf, accL[qh], 0, 0, 0); \
      }                                                                       \
  } while (0)

    __syncthreads();                       // phase-1 LDS fully consumed
    STAGE(0, K0, V0);
    for (int kt = 0; kt < 8; kt += 2) {
      __syncthreads();                     // drains tile kt loads (buf0)
      STAGE(kt + 1, K1, V1);               // prefetch next into buf1
      COMPUTE(K0, V0);
      __syncthreads();                     // drains tile kt+1 loads (buf1)
      if (kt + 2 < 8) STAGE(kt + 2, K0, V0);
      COMPUTE(K1, V1);
    }
#undef STAGE
#undef COMPUTE

    unsigned short* obase = Opart + (size_t)(qb * 8 + ks) * 256 * HD;
#pragma unroll
    for (int qh = 0; qh < 4; ++qh) {
      int qlocal = 64 * w + 16 * qh + lr;
#pragma unroll
      for (int t = 0; t < 4; ++t) {
        uint2 u;
        u.x = pack_f16(accO[qh][t][0], accO[qh][t][1]);
        u.y = pack_f16(accO[qh][t][2], accO[qh][t][3]);
        *(uint2*)(obase + qlocal * HD + 16 * t + 4 * g) = u;
      }
      if (g == 0) Lpart[(qb * 8 + ks) * 256 + qlocal] = accL[qh][0];
    }
  }

  grid.sync();   // Opart/Lpart visible grid-wide

  // ======================= Phase 3: combine =======================
  {
#pragma unroll
    for (int it = 0; it < 2; ++it) {
      int t   = blockIdx.x * 512 + it * 256 + tid;   // 0..262143
      int row = t >> 4;                              // global q row
      int d0  = (t & 15) * 4;
      int qb2 = row >> 8, qi = row & 255;
      float4 acc = {0.f, 0.f, 0.f, 0.f};
      float lt = 0.0f;
#pragma unroll
      for (int k2 = 0; k2 < 8; ++k2) {
        const unsigned short* p = Opart + ((size_t)(qb2 * 8 + k2) * 256 + qi) * HD + d0;
        ushort4 v = *(const ushort4*)p;
        acc.x += f16_to_f32(v.x);
        acc.y += f16_to_f32(v.y);
        acc.z += f16_to_f32(v.z);
        acc.w += f16_to_f32(v.w);
        lt += Lpart[(qb2 * 8 + k2) * 256 + qi];
      }
      float inv = 1.0f / lt;
      float4 o = {acc.x * inv, acc.y * inv, acc.z * inv, acc.w * inv};
      *(float4*)(out + (size_t)row * HD + d0) = o;
    }
  }
}

// ---------------------------------------------------------------------------
// Fallback path (known-good R1 kernels) in case cooperative launch fails.
// ---------------------------------------------------------------------------
__global__ __launch_bounds__(256) void proj_kernel(
    const float* __restrict__ x,
    const unsigned short* __restrict__ Wpk,
    unsigned short* __restrict__ Qb,
    unsigned short* __restrict__ Kb,
    unsigned short* __restrict__ VTb)
{
  __shared__ __align__(16) unsigned short Xh[2][32 * XST];
  __shared__ __align__(16) unsigned short Xl[2][32 * XST];

  const int tid  = threadIdx.x;
  const int lane = tid & 63;
  const int w    = tid >> 6;
  const int lr   = lane & 15, g = lane >> 4;
  const long rowBase = (long)blockIdx.x * 32;

  floatx4 accQ[2], accK[2], accV[2];
#pragma unroll
  for (int rt = 0; rt < 2; ++rt) {
    floatx4 z = {0.f, 0.f, 0.f, 0.f};
    accQ[rt] = z; accK[rt] = z; accV[rt] = z;
  }

  const int srow = tid >> 3;
  const int sc   = 4 * (tid & 7);
  const float* xbase = x + (rowBase + srow) * EMB + sc;

  auto stage_write = [&](float4 v, int buf) {
    float vv[4] = {v.x, v.y, v.z, v.w};
    ushort4 hi, lo;
#pragma unroll
    for (int i = 0; i < 4; ++i) {
      unsigned short h = f2bf(vv[i]);
      ((unsigned short*)&hi)[i] = h;
      ((unsigned short*)&lo)[i] = f2bf(vv[i] - bf2f(h));
    }
    *(ushort4*)&Xh[buf][srow * XST + sc] = hi;
    *(ushort4*)&Xl[buf][srow * XST + sc] = lo;
  };

  short8 Wb[2][4];
  {
    const unsigned short* wb_ = Wpk + (size_t)(w * 16) * 512 + lane * 8;
    Wb[0][0] = *(const short8*)(wb_);
    Wb[0][1] = *(const short8*)(wb_ + 32768);
    Wb[0][2] = *(const short8*)(wb_ + 2 * 32768);
    Wb[0][3] = *(const short8*)(wb_ + 3 * 32768);
  }

  float4 xv = *(const float4*)(xbase);
  stage_write(xv, 0);
  float4 xn1 = *(const float4*)(xbase + 32);
  float4 xn2 = *(const float4*)(xbase + 64);
  float4 xn3 = *(const float4*)(xbase + 96);

#pragma unroll 2
  for (int kc = 0; kc < 16; ++kc) {
    if (kc + 1 < 16) {
      const unsigned short* wb_ = Wpk + (size_t)(w * 16 + kc + 1) * 512 + lane * 8;
      Wb[(kc + 1) & 1][0] = *(const short8*)(wb_);
      Wb[(kc + 1) & 1][1] = *(const short8*)(wb_ + 32768);
      Wb[(kc + 1) & 1][2] = *(const short8*)(wb_ + 2 * 32768);
      Wb[(kc + 1) & 1][3] = *(const short8*)(wb_ + 3 * 32768);
    }
    float4 xfut;
    if (kc + 4 < 16) xfut = *(const float4*)(xbase + (kc + 4) * 32);
    __syncthreads();
    const int buf = kc & 1;
#pragma unroll
    for (int rt = 0; rt < 2; ++rt) {
      short8 xh = *(const short8*)&Xh[buf][(16 * rt + lr) * XST + 8 * g];
      short8 xl = *(const short8*)&Xl[buf][(16 * rt + lr) * XST + 8 * g];
      accQ[rt] = __builtin_amdgcn_mfma_f32_16x16x32_bf16(Wb[buf][0], xh, accQ[rt], 0, 0, 0);
      accK[rt] = __builtin_amdgcn_mfma_f32_16x16x32_bf16(Wb[buf][1], xh, accK[rt], 0, 0, 0);
      accV[rt] = __builtin_amdgcn_mfma_f32_16x16x32_bf16(xh, Wb[buf][2], accV[rt], 0, 0, 0);
      accV[rt] = __builtin_amdgcn_mfma_f32_16x16x32_bf16(xl, Wb[buf][2], accV[rt], 0, 0, 0);
      accV[rt] = __builtin_amdgcn_mfma_f32_16x16x32_bf16(xh, Wb[buf][3], accV[rt], 0, 0, 0);
    }
    if (kc + 1 < 16) { stage_write(xn1, (kc + 1) & 1); xn1 = xn2; xn2 = xn3; xn3 = xfut; }
  }

  const int bb  = (int)(rowBase >> 12);
  const int sIn = (int)(rowBase & 4095);
#pragma unroll
  for (int rt = 0; rt < 2; ++rt) {
    {
      long row = rowBase + 16 * rt + lr;
      int  col = 16 * w + 4 * g;
      ushort4 u; u.x = f2bf(accQ[rt][0]); u.y = f2bf(accQ[rt][1]);
      u.z = f2bf(accQ[rt][2]); u.w = f2bf(accQ[rt][3]);
      *(ushort4*)(Qb + row * HD + col) = u;
      ushort4 v; v.x = f2bf(accK[rt][0]); v.y = f2bf(accK[rt][1]);
      v.z = f2bf(accK[rt][2]); v.w = f2bf(accK[rt][3]);
      *(ushort4*)(Kb + row * HD + col) = v;
    }
    {
      long addr = ((long)(bb * 64 + 16 * w + lr)) * SEQ + sIn + 16 * rt + 4 * g;
      ushort4 u; u.x = f2bf(accV[rt][0]); u.y = f2bf(accV[rt][1]);
      u.z = f2bf(accV[rt][2]); u.w = f2bf(accV[rt][3]);
      *(ushort4*)(VTb + addr) = u;
    }
  }
}

__global__ __launch_bounds__(256, 2) void flash_kernel(
    const unsigned short* __restrict__ Qb,
    const unsigned short* __restrict__ Kb,
    const unsigned short* __restrict__ VTb,
    unsigned short* __restrict__ Opart,
    float* __restrict__ Lpart)
{
  __shared__ __align__(16) unsigned short K0lds[64 * 64];
  __shared__ __align__(16) unsigned short V0lds[64 * 64];
  __shared__ __align__(16) unsigned short K1lds[64 * 64];
  __shared__ __align__(16) unsigned short V1lds[64 * 64];
  __shared__ __align__(16) unsigned short Plds[4][64 * PST];

  const int tid  = threadIdx.x;
  const int lane = tid & 63;
  const int w    = tid >> 6;
  const int lr   = lane & 15, g = lane >> 4;
  const int qb   = blockIdx.x >> 3;
  const int ks   = blockIdx.x & 7;
  const int bb   = qb >> 4;
  const long qrow0 = (long)qb * 256 + 64 * w;
  const int  kbase = ks * 512;

  short8 qf[4][2];
#pragma unroll
  for (int qh = 0; qh < 4; ++qh)
#pragma unroll
    for (int ec = 0; ec < 2; ++ec)
      qf[qh][ec] = *(const short8*)(Qb + (qrow0 + 16 * qh + lr) * HD + ec * 32 + 8 * g);

  floatx4 accO[4][4];
  floatx4 accL[4];
#pragma unroll
  for (int qh = 0; qh < 4; ++qh) {
    floatx4 z = {0.f, 0.f, 0.f, 0.f};
#pragma unroll
    for (int t = 0; t < 4; ++t) accO[qh][t] = z;
    accL[qh] = z;
  }
  short8 onesf;
#pragma unroll
  for (int j = 0; j < 8; ++j) onesf[j] = (short)0x3F80;

  const float cp = 0.18033688011112042f;
  const float SH = 2.0f;

#define STAGE(kt_, KL, VL) do {                                               \
    const int k0_ = kbase + (kt_) * 64;                                       \
    _Pragma("unroll")                                                         \
    for (int h_ = 0; h_ < 2; ++h_) {                                          \
      int ci_  = h_ * 256 + tid;                                              \
      int row_ = ci_ >> 3;                                                    \
      int cc_  = (ci_ & 7) ^ (row_ & 7);                                      \
      const unsigned short* gK_ = Kb + ((long)bb * SEQ + k0_ + row_) * HD + cc_ * 8; \
      __builtin_amdgcn_global_load_lds(                                       \
          (const __attribute__((address_space(1))) void*)gK_,                 \
          (__attribute__((address_space(3))) void*)((KL) + ci_ * 8), 16, 0, 0); \
      const unsigned short* gV_ = VTb + ((long)bb * HD + row_) * SEQ + k0_ + cc_ * 8; \
      __builtin_amdgcn_global_load_lds(                                       \
          (const __attribute__((address_space(1))) void*)gV_,                 \
          (__attribute__((address_space(3))) void*)((VL) + ci_ * 8), 16, 0, 0); \
    }                                                                         \
  } while (0)

#define COMPUTE(KL, VL) do {                                                  \
    short8 kf[2][4];                                                          \
    _Pragma("unroll")                                                         \
    for (int ec = 0; ec < 2; ++ec)                                            \
      _Pragma("unroll")                                                       \
      for (int t = 0; t < 4; ++t) {                                           \
        int key  = 16 * t + lr;                                               \
        int slot = key * 8 + ((4 * ec + g) ^ (key & 7));                      \
        kf[ec][t] = *(const short8*)((KL) + slot * 8);                        \
      }                                                                       \
    _Pragma("unroll")                                                         \
    for (int qh = 0; qh < 4; ++qh) {                                          \
      floatx4 s_[4];                                                          \
      _Pragma("unroll")                                                       \
      for (int t = 0; t < 4; ++t) { floatx4 z = {0.f,0.f,0.f,0.f}; s_[t] = z; } \
      _Pragma("unroll")                                                       \
      for (int ec = 0; ec < 2; ++ec)                                          \
        _Pragma("unroll")                                                     \
        for (int t = 0; t < 4; ++t)                                           \
          s_[t] = __builtin_amdgcn_mfma_f32_16x16x32_bf16(kf[ec][t], qf[qh][ec], s_[t], 0, 0, 0); \
      unsigned short* prow = &Plds[w][(16 * qh + lr) * PST];                  \
      _Pragma("unroll")                                                       \
      for (int t = 0; t < 4; ++t) {                                           \
        float p0 = __builtin_amdgcn_exp2f(__builtin_fmaf(s_[t][0], cp, -SH)); \
        float p1 = __builtin_amdgcn_exp2f(__builtin_fmaf(s_[t][1], cp, -SH)); \
        float p2 = __builtin_amdgcn_exp2f(__builtin_fmaf(s_[t][2], cp, -SH)); \
        float p3 = __builtin_amdgcn_exp2f(__builtin_fmaf(s_[t][3], cp, -SH)); \
        uint2 u;                                                              \
        u.x = pack_hi16(p0, p1);                                              \
        u.y = pack_hi16(p2, p3);                                              \
        *(uint2*)(prow + 16 * t + 4 * g) = u;                                 \
      }                                                                       \
    }                                                                         \
    short8 vf[2][4];                                                          \
    _Pragma("unroll")                                                         \
    for (int c = 0; c < 2; ++c)                                               \
      _Pragma("unroll")                                                       \
      for (int t = 0; t < 4; ++t) {                                           \
        int d    = 16 * t + lr;                                               \
        int slot = d * 8 + ((4 * c + g) ^ (d & 7));                           \
        vf[c][t] = *(const short8*)((VL) + slot * 8);                        \
      }                                                                       \
    _Pragma("unroll")                                                         \
    for (int qh = 0; qh < 4; ++qh)                                            \
      _Pragma("unroll")                                                       \
      for (int c = 0; c < 2; ++c) {                                           \
        short8 pf = *(const short8*)(&Plds[w][(16 * qh + lr) * PST + 32 * c + 8 * g]); \
        _Pragma("unroll")                                                     \
        for (int t = 0; t < 4; ++t)                                           \
          accO[qh][t] = __builtin_amdgcn_mfma_f32_16x16x32_bf16(vf[c][t], pf, accO[qh][t], 0, 0, 0); \
        accL[qh] = __builtin_amdgcn_mfma_f32_16x16x32_bf16(onesf, pf, accL[qh], 0, 0, 0); \
      }                                                                       \
  } while (0)

  STAGE(0, K0lds, V0lds);
  for (int kt = 0; kt < 8; kt += 2) {
    __syncthreads();
    STAGE(kt + 1, K1lds, V1lds);
    COMPUTE(K0lds, V0lds);
    __syncthreads();
    if (kt + 2 < 8) STAGE(kt + 2, K0lds, V0lds);
    COMPUTE(K1lds, V1lds);
  }
#undef STAGE
#undef COMPUTE

  unsigned short* obase = Opart + (size_t)(qb * 8 + ks) * 256 * HD;
#pragma unroll
  for (int qh = 0; qh < 4; ++qh) {
    int qlocal = 64 * w + 16 * qh + lr;
#pragma unroll
    for (int t = 0; t < 4; ++t) {
      uint2 u;
      u.x = pack_f16(accO[qh][t][0], accO[qh][t][1]);
      u.y = pack_f16(accO[qh][t][2], accO[qh][t][3]);
      *(uint2*)(obase + qlocal * HD + 16 * t + 4 * g) = u;
    }
    if (g == 0) Lpart[(qb * 8 + ks) * 256 + qlocal] = accL[qh][0];
  }
}

__global__ __launch_bounds__(256) void combine_kernel(
    const unsigned short* __restrict__ Opart, const float* __restrict__ Lpart,
    float* __restrict__ out)
{
  int t   = blockIdx.x * 256 + threadIdx.x;
  int row = t >> 4;
  int d0  = (t & 15) * 4;
  int qb = row >> 8, qi = row & 255;
  float4 acc = {0.f, 0.f, 0.f, 0.f};
  float lt = 0.0f;
#pragma unroll
  for (int ks = 0; ks < 8; ++ks) {
    const unsigned short* p = Opart + ((size_t)(qb * 8 + ks) * 256 + qi) * HD + d0;
    ushort4 v = *(const ushort4*)p;
    acc.x += f16_to_f32(v.x);
    acc.y += f16_to_f32(v.y);
    acc.z += f16_to_f32(v.z);
    acc.w += f16_to_f32(v.w);
    lt += Lpart[(qb * 8 + ks) * 256 + qi];
  }
  float inv = 1.0f / lt;
  float4 o = {acc.x * inv, acc.y * inv, acc.z * inv, acc.w * inv};
  *(float4*)(out + (size_t)row * HD + d0) = o;
}

extern "C" void kernel_launch(void* const* d_in, const int* in_sizes, int n_in,
                              void* d_out, int out_size, void* d_ws, size_t ws_size,
                              hipStream_t stream) {
  const float* x  = (const float*)d_in[0];
  const float* WQ = (const float*)d_in[1];
  const float* WK = (const float*)d_in[2];
  const float* WV = (const float*)d_in[3];

  unsigned short* Qb  = (unsigned short*)d_ws;                  // [16384][64] bf16
  unsigned short* Kb  = Qb  + (size_t)BATCH * SEQ * HD;         // [16384][64] bf16
  unsigned short* VTb = Kb  + (size_t)BATCH * SEQ * HD;         // [4][64][4096] bf16
  unsigned short* Wpk = VTb + (size_t)BATCH * SEQ * HD;         // 262144 shorts
  unsigned short* Opart = Wpk + 262144;                         // fp16 [512][256][64]
  float* Lpart = (float*)(Opart + (size_t)512 * 256 * HD);      // [512][256] f32

  convw_kernel<<<64, 256, 0, stream>>>(WQ, WK, WV, Wpk);

  const float* x_ = x;
  const unsigned short* Wpk_ = Wpk;
  unsigned short* Qb_ = Qb;
  unsigned short* Kb_ = Kb;
  unsigned short* VTb_ = VTb;
  unsigned short* Op_ = Opart;
  float* Lp_ = Lpart;
  float* out_ = (float*)d_out;
  void* args[] = {(void*)&x_, (void*)&Wpk_, (void*)&Qb_, (void*)&Kb_,
                  (void*)&VTb_, (void*)&Op_, (void*)&Lp_, (void*)&out_};
  hipError_t e = hipLaunchCooperativeKernel((const void*)mega_kernel,
                                            dim3(512), dim3(256), args, 0,
                                            stream);
  if (e != hipSuccess) {
    // fallback: known-good three-kernel path
    proj_kernel<<<(BATCH * SEQ) / 32, 256, 0, stream>>>(x, Wpk, Qb, Kb, VTb);
    flash_kernel<<<512, 256, 0, stream>>>(Qb, Kb, VTb, Opart, Lpart);
    combine_kernel<<<1024, 256, 0, stream>>>(Opart, Lpart, (float*)d_out);
  }
}

// Round 5
// 129.397 us; speedup vs baseline: 2.0338x; 2.0338x over previous
//
#include <hip/hip_runtime.h>

#define BATCH 4
#define SEQ   4096
#define EMB   512
#define HD    64

typedef __attribute__((ext_vector_type(8))) short short8;
typedef __attribute__((ext_vector_type(4))) float floatx4;

static __device__ __forceinline__ unsigned short f2bf(float f) {
  unsigned u = __builtin_bit_cast(unsigned, f);
  u += 0x7fffu + ((u >> 16) & 1u);           // round-to-nearest-even
  return (unsigned short)(u >> 16);
}
static __device__ __forceinline__ float bf2f(unsigned short h) {
  unsigned u = ((unsigned)h) << 16;
  return __builtin_bit_cast(float, u);
}
static __device__ __forceinline__ unsigned pack_hi16(float lo, float hi) {
#if __has_builtin(__builtin_amdgcn_perm)
  return __builtin_amdgcn_perm(__builtin_bit_cast(unsigned, hi),
                               __builtin_bit_cast(unsigned, lo), 0x07060302u);
#else
  return (__builtin_bit_cast(unsigned, lo) >> 16) |
         (__builtin_bit_cast(unsigned, hi) & 0xffff0000u);
#endif
}
static __device__ __forceinline__ unsigned pack_f16(float a, float b) {
#if __has_builtin(__builtin_amdgcn_cvt_pkrtz)
  typedef __fp16 fp16v2 __attribute__((ext_vector_type(2)));
  fp16v2 h = __builtin_amdgcn_cvt_pkrtz(a, b);
  return __builtin_bit_cast(unsigned, h);
#else
  _Float16 ha = (_Float16)a, hb = (_Float16)b;
  return (unsigned)__builtin_bit_cast(unsigned short, ha) |
         ((unsigned)__builtin_bit_cast(unsigned short, hb) << 16);
#endif
}
static __device__ __forceinline__ float f16_to_f32(unsigned short bits) {
  _Float16 h = __builtin_bit_cast(_Float16, bits);
  return (float)h;
}

// ---------------------------------------------------------------------------
// Kernel 0: pack W into MFMA fragment order, bf16. (verified)
// ---------------------------------------------------------------------------
__global__ __launch_bounds__(256) void convw_kernel(
    const float* __restrict__ WQ, const float* __restrict__ WK,
    const float* __restrict__ WV, unsigned short* __restrict__ Wpk)
{
  int t = blockIdx.x * 256 + threadIdx.x;     // 0..16383
  int p    = t >> 12;
  int w    = (t >> 10) & 3;
  int kc   = (t >> 6) & 15;
  int lane = t & 63;
  int lr = lane & 15, g = lane >> 4;
  const float* src = (p == 0) ? WQ : ((p == 1) ? WK : WV);
  const float4* s4 = (const float4*)(src + (16 * w + lr) * EMB + kc * 32 + 8 * g);
  float4 a = s4[0], b = s4[1];
  float vv[8] = {a.x, a.y, a.z, a.w, b.x, b.y, b.z, b.w};
  short8 o;
#pragma unroll
  for (int j = 0; j < 8; ++j) {
    unsigned short h = f2bf(vv[j]);
    o[j] = (p == 3) ? (short)f2bf(vv[j] - bf2f(h)) : (short)h;
  }
  *(short8*)(Wpk + (size_t)t * 8) = o;
}

// ---------------------------------------------------------------------------
// Kernel 1: QKV projection. (verified; unchanged)
// ---------------------------------------------------------------------------
#define XST 40   // LDS x row stride in shorts

__global__ __launch_bounds__(256) void proj_kernel(
    const float* __restrict__ x,
    const unsigned short* __restrict__ Wpk,
    unsigned short* __restrict__ Qb,
    unsigned short* __restrict__ Kb,
    unsigned short* __restrict__ VTb)
{
  __shared__ __align__(16) unsigned short Xh[2][32 * XST];
  __shared__ __align__(16) unsigned short Xl[2][32 * XST];

  const int tid  = threadIdx.x;
  const int lane = tid & 63;
  const int w    = tid >> 6;
  const int lr   = lane & 15, g = lane >> 4;
  const long rowBase = (long)blockIdx.x * 32;

  floatx4 accQ[2], accK[2], accV[2];
#pragma unroll
  for (int rt = 0; rt < 2; ++rt) {
    floatx4 z = {0.f, 0.f, 0.f, 0.f};
    accQ[rt] = z; accK[rt] = z; accV[rt] = z;
  }

  const int srow = tid >> 3;
  const int sc   = 4 * (tid & 7);
  const float* xbase = x + (rowBase + srow) * EMB + sc;

  auto stage_write = [&](float4 v, int buf) {
    float vv[4] = {v.x, v.y, v.z, v.w};
    ushort4 hi, lo;
#pragma unroll
    for (int i = 0; i < 4; ++i) {
      unsigned short h = f2bf(vv[i]);
      ((unsigned short*)&hi)[i] = h;
      ((unsigned short*)&lo)[i] = f2bf(vv[i] - bf2f(h));
    }
    *(ushort4*)&Xh[buf][srow * XST + sc] = hi;
    *(ushort4*)&Xl[buf][srow * XST + sc] = lo;
  };

  short8 Wb[2][4];
  {
    const unsigned short* wb_ = Wpk + (size_t)(w * 16) * 512 + lane * 8;
    Wb[0][0] = *(const short8*)(wb_);
    Wb[0][1] = *(const short8*)(wb_ + 32768);
    Wb[0][2] = *(const short8*)(wb_ + 2 * 32768);
    Wb[0][3] = *(const short8*)(wb_ + 3 * 32768);
  }

  float4 xv = *(const float4*)(xbase);
  stage_write(xv, 0);
  float4 xn1 = *(const float4*)(xbase + 32);
  float4 xn2 = *(const float4*)(xbase + 64);
  float4 xn3 = *(const float4*)(xbase + 96);

#pragma unroll 2
  for (int kc = 0; kc < 16; ++kc) {
    if (kc + 1 < 16) {
      const unsigned short* wb_ = Wpk + (size_t)(w * 16 + kc + 1) * 512 + lane * 8;
      Wb[(kc + 1) & 1][0] = *(const short8*)(wb_);
      Wb[(kc + 1) & 1][1] = *(const short8*)(wb_ + 32768);
      Wb[(kc + 1) & 1][2] = *(const short8*)(wb_ + 2 * 32768);
      Wb[(kc + 1) & 1][3] = *(const short8*)(wb_ + 3 * 32768);
    }
    float4 xfut;
    if (kc + 4 < 16) xfut = *(const float4*)(xbase + (kc + 4) * 32);
    __syncthreads();
    const int buf = kc & 1;
#pragma unroll
    for (int rt = 0; rt < 2; ++rt) {
      short8 xh = *(const short8*)&Xh[buf][(16 * rt + lr) * XST + 8 * g];
      short8 xl = *(const short8*)&Xl[buf][(16 * rt + lr) * XST + 8 * g];
      accQ[rt] = __builtin_amdgcn_mfma_f32_16x16x32_bf16(Wb[buf][0], xh, accQ[rt], 0, 0, 0);
      accK[rt] = __builtin_amdgcn_mfma_f32_16x16x32_bf16(Wb[buf][1], xh, accK[rt], 0, 0, 0);
      accV[rt] = __builtin_amdgcn_mfma_f32_16x16x32_bf16(xh, Wb[buf][2], accV[rt], 0, 0, 0);
      accV[rt] = __builtin_amdgcn_mfma_f32_16x16x32_bf16(xl, Wb[buf][2], accV[rt], 0, 0, 0);
      accV[rt] = __builtin_amdgcn_mfma_f32_16x16x32_bf16(xh, Wb[buf][3], accV[rt], 0, 0, 0);
    }
    if (kc + 1 < 16) { stage_write(xn1, (kc + 1) & 1); xn1 = xn2; xn2 = xn3; xn3 = xfut; }
  }

  const int bb  = (int)(rowBase >> 12);
  const int sIn = (int)(rowBase & 4095);
#pragma unroll
  for (int rt = 0; rt < 2; ++rt) {
    {
      long row = rowBase + 16 * rt + lr;
      int  col = 16 * w + 4 * g;
      ushort4 u; u.x = f2bf(accQ[rt][0]); u.y = f2bf(accQ[rt][1]);
      u.z = f2bf(accQ[rt][2]); u.w = f2bf(accQ[rt][3]);
      *(ushort4*)(Qb + row * HD + col) = u;
      ushort4 v; v.x = f2bf(accK[rt][0]); v.y = f2bf(accK[rt][1]);
      v.z = f2bf(accK[rt][2]); v.w = f2bf(accK[rt][3]);
      *(ushort4*)(Kb + row * HD + col) = v;
    }
    {
      long addr = ((long)(bb * 64 + 16 * w + lr)) * SEQ + sIn + 16 * rt + 4 * g;
      ushort4 u; u.x = f2bf(accV[rt][0]); u.y = f2bf(accV[rt][1]);
      u.z = f2bf(accV[rt][2]); u.w = f2bf(accV[rt][3]);
      *(ushort4*)(VTb + addr) = u;
    }
  }
}

// ---------------------------------------------------------------------------
// Kernel 2: flash attention — BARRIER-FREE. The K/V slice per (bb,ks) is
// 64+64 KB = L2-resident (16 blocks share it, XCD-pinned via ks). Per
// Common-mistake #7, LDS staging of L2-fit data is pure overhead: K and V
// fragments are now read DIRECTLY from global (16 B/lane, coalesced,
// issued at tile top so QK^T+softmax covers the ~200 cyc L2 latency).
// LDS holds only the per-wave P buffer -> ZERO __syncthreads in the k-loop.
// l is an extra ones-MFMA (verified in R1). Partial layout unchanged.
// ---------------------------------------------------------------------------
#define PST 72   // P row stride in shorts: 144 B (16B-mult)

__global__ __launch_bounds__(256, 2) void flash_kernel(
    const unsigned short* __restrict__ Qb,
    const unsigned short* __restrict__ Kb,
    const unsigned short* __restrict__ VTb,
    unsigned short* __restrict__ Opart,   // fp16 bits [64*8][256][64]
    float* __restrict__ Lpart)            // [64*8][256]
{
  __shared__ __align__(16) unsigned short Plds[4][64 * PST];   // 36864 B

  const int tid  = threadIdx.x;
  const int lane = tid & 63;
  const int w    = tid >> 6;
  const int lr   = lane & 15, g = lane >> 4;
  const int qb   = blockIdx.x >> 3;      // 0..63
  const int ks   = blockIdx.x & 7;       // K split (XCD-pinned)
  const int bb   = qb >> 4;              // batch
  const long qrow0 = (long)qb * 256 + 64 * w;
  const int  kbase = ks * 512;

  short8 qf[4][2];
#pragma unroll
  for (int qh = 0; qh < 4; ++qh)
#pragma unroll
    for (int ec = 0; ec < 2; ++ec)
      qf[qh][ec] = *(const short8*)(Qb + (qrow0 + 16 * qh + lr) * HD + ec * 32 + 8 * g);

  floatx4 accO[4][4];
  floatx4 accL[4];
#pragma unroll
  for (int qh = 0; qh < 4; ++qh) {
    floatx4 z = {0.f, 0.f, 0.f, 0.f};
#pragma unroll
    for (int t = 0; t < 4; ++t) accO[qh][t] = z;
    accL[qh] = z;
  }
  short8 onesf;
#pragma unroll
  for (int j = 0; j < 8; ++j) onesf[j] = (short)0x3F80;

  const float cp = 0.18033688011112042f;   // (1/sqrt(64)) * log2(e)
  const float SH = 2.0f;                   // fixed shift (exp2 domain), exact

  // fragment base pointers:
  //  K[key = kbase + kt*64 + 16t + lr][e = 32ec + 8g ..+8)
  const unsigned short* kfb = Kb + ((long)bb * SEQ + kbase + lr) * HD + 8 * g;
  //  V^T[d = 16t + lr][key = kbase + kt*64 + 32c + 8g ..+8)
  const unsigned short* vfb = VTb + ((long)bb * HD + lr) * SEQ + kbase + 8 * g;

  unsigned short* Pw = &Plds[w][0];

  for (int kt = 0; kt < 8; ++kt) {
    // issue ALL of this tile's global loads first (in-order vmcnt FIFO:
    // K first -> QK^T waits only for K; V lands during QK^T + softmax)
    short8 kf[2][4];
#pragma unroll
    for (int ec = 0; ec < 2; ++ec)
#pragma unroll
      for (int t = 0; t < 4; ++t)
        kf[ec][t] = *(const short8*)(kfb + (long)(kt * 64 + 16 * t) * HD + 32 * ec);
    short8 vf[2][4];
#pragma unroll
    for (int c = 0; c < 2; ++c)
#pragma unroll
      for (int t = 0; t < 4; ++t)
        vf[c][t] = *(const short8*)(vfb + (long)(16 * t) * SEQ + kt * 64 + 32 * c);

    // QK^T + softmax -> per-wave P (LDS)
#pragma unroll
    for (int qh = 0; qh < 4; ++qh) {
      floatx4 s_[4];
#pragma unroll
      for (int t = 0; t < 4; ++t) { floatx4 z = {0.f, 0.f, 0.f, 0.f}; s_[t] = z; }
#pragma unroll
      for (int ec = 0; ec < 2; ++ec)
#pragma unroll
        for (int t = 0; t < 4; ++t)
          s_[t] = __builtin_amdgcn_mfma_f32_16x16x32_bf16(kf[ec][t], qf[qh][ec], s_[t], 0, 0, 0);
      unsigned short* prow = Pw + (16 * qh + lr) * PST;
#pragma unroll
      for (int t = 0; t < 4; ++t) {
        float p0 = __builtin_amdgcn_exp2f(__builtin_fmaf(s_[t][0], cp, -SH));
        float p1 = __builtin_amdgcn_exp2f(__builtin_fmaf(s_[t][1], cp, -SH));
        float p2 = __builtin_amdgcn_exp2f(__builtin_fmaf(s_[t][2], cp, -SH));
        float p3 = __builtin_amdgcn_exp2f(__builtin_fmaf(s_[t][3], cp, -SH));
        uint2 u;
        u.x = pack_hi16(p0, p1);
        u.y = pack_hi16(p2, p3);
        *(uint2*)(prow + 16 * t + 4 * g) = u;
      }
    }

    // PV: P fragments from per-wave LDS (lgkmcnt ordering, no barrier)
#pragma unroll
    for (int qh = 0; qh < 4; ++qh)
#pragma unroll
      for (int c = 0; c < 2; ++c) {
        short8 pf = *(const short8*)(Pw + (16 * qh + lr) * PST + 32 * c + 8 * g);
#pragma unroll
        for (int t = 0; t < 4; ++t)
          accO[qh][t] = __builtin_amdgcn_mfma_f32_16x16x32_bf16(vf[c][t], pf, accO[qh][t], 0, 0, 0);
        accL[qh] = __builtin_amdgcn_mfma_f32_16x16x32_bf16(onesf, pf, accL[qh], 0, 0, 0);
      }
  }

  // epilogue: store fp16 O partials + fp32 l
  unsigned short* obase = Opart + (size_t)(qb * 8 + ks) * 256 * HD;
#pragma unroll
  for (int qh = 0; qh < 4; ++qh) {
    int qlocal = 64 * w + 16 * qh + lr;
#pragma unroll
    for (int t = 0; t < 4; ++t) {
      uint2 u;
      u.x = pack_f16(accO[qh][t][0], accO[qh][t][1]);
      u.y = pack_f16(accO[qh][t][2], accO[qh][t][3]);
      *(uint2*)(obase + qlocal * HD + 16 * t + 4 * g) = u;
    }
    if (g == 0) Lpart[(qb * 8 + ks) * 256 + qlocal] = accL[qh][0];
  }
}

// ---------------------------------------------------------------------------
// Kernel 3: combine split-K partials. (verified; unchanged)
// ---------------------------------------------------------------------------
__global__ __launch_bounds__(256) void combine_kernel(
    const unsigned short* __restrict__ Opart, const float* __restrict__ Lpart,
    float* __restrict__ out)
{
  int t   = blockIdx.x * 256 + threadIdx.x;    // 0..262143
  int row = t >> 4;
  int d0  = (t & 15) * 4;
  int qb = row >> 8, qi = row & 255;
  float4 acc = {0.f, 0.f, 0.f, 0.f};
  float lt = 0.0f;
#pragma unroll
  for (int ks = 0; ks < 8; ++ks) {
    const unsigned short* p = Opart + ((size_t)(qb * 8 + ks) * 256 + qi) * HD + d0;
    ushort4 v = *(const ushort4*)p;
    acc.x += f16_to_f32(v.x);
    acc.y += f16_to_f32(v.y);
    acc.z += f16_to_f32(v.z);
    acc.w += f16_to_f32(v.w);
    lt += Lpart[(qb * 8 + ks) * 256 + qi];
  }
  float inv = 1.0f / lt;
  float4 o = {acc.x * inv, acc.y * inv, acc.z * inv, acc.w * inv};
  *(float4*)(out + (size_t)row * HD + d0) = o;
}

extern "C" void kernel_launch(void* const* d_in, const int* in_sizes, int n_in,
                              void* d_out, int out_size, void* d_ws, size_t ws_size,
                              hipStream_t stream) {
  const float* x  = (const float*)d_in[0];
  const float* WQ = (const float*)d_in[1];
  const float* WK = (const float*)d_in[2];
  const float* WV = (const float*)d_in[3];

  unsigned short* Qb  = (unsigned short*)d_ws;                  // [16384][64] bf16
  unsigned short* Kb  = Qb  + (size_t)BATCH * SEQ * HD;         // [16384][64] bf16
  unsigned short* VTb = Kb  + (size_t)BATCH * SEQ * HD;         // [4][64][4096] bf16
  unsigned short* Wpk = VTb + (size_t)BATCH * SEQ * HD;         // 262144 shorts
  unsigned short* Opart = Wpk + 262144;                         // fp16 [512][256][64]
  float* Lpart = (float*)(Opart + (size_t)512 * 256 * HD);      // [512][256] f32

  convw_kernel<<<64, 256, 0, stream>>>(WQ, WK, WV, Wpk);
  proj_kernel<<<(BATCH * SEQ) / 32, 256, 0, stream>>>(x, Wpk, Qb, Kb, VTb);
  flash_kernel<<<512, 256, 0, stream>>>(Qb, Kb, VTb, Opart, Lpart);
  combine_kernel<<<1024, 256, 0, stream>>>(Opart, Lpart, (float*)d_out);
}

// Round 6
// 116.633 us; speedup vs baseline: 2.2563x; 1.1094x over previous
//
#include <hip/hip_runtime.h>

#define BATCH 4
#define SEQ   4096
#define EMB   512
#define HD    64

typedef __attribute__((ext_vector_type(8))) short short8;
typedef __attribute__((ext_vector_type(4))) float floatx4;

static __device__ __forceinline__ unsigned short f2bf(float f) {
  unsigned u = __builtin_bit_cast(unsigned, f);
  u += 0x7fffu + ((u >> 16) & 1u);           // round-to-nearest-even
  return (unsigned short)(u >> 16);
}
static __device__ __forceinline__ float bf2f(unsigned short h) {
  unsigned u = ((unsigned)h) << 16;
  return __builtin_bit_cast(float, u);
}
static __device__ __forceinline__ unsigned pack_hi16(float lo, float hi) {
#if __has_builtin(__builtin_amdgcn_perm)
  return __builtin_amdgcn_perm(__builtin_bit_cast(unsigned, hi),
                               __builtin_bit_cast(unsigned, lo), 0x07060302u);
#else
  return (__builtin_bit_cast(unsigned, lo) >> 16) |
         (__builtin_bit_cast(unsigned, hi) & 0xffff0000u);
#endif
}
static __device__ __forceinline__ unsigned pack_f16(float a, float b) {
#if __has_builtin(__builtin_amdgcn_cvt_pkrtz)
  typedef __fp16 fp16v2 __attribute__((ext_vector_type(2)));
  fp16v2 h = __builtin_amdgcn_cvt_pkrtz(a, b);
  return __builtin_bit_cast(unsigned, h);
#else
  _Float16 ha = (_Float16)a, hb = (_Float16)b;
  return (unsigned)__builtin_bit_cast(unsigned short, ha) |
         ((unsigned)__builtin_bit_cast(unsigned short, hb) << 16);
#endif
}
static __device__ __forceinline__ float f16_to_f32(unsigned short bits) {
  _Float16 h = __builtin_bit_cast(_Float16, bits);
  return (float)h;
}

// ---------------------------------------------------------------------------
// Kernel 0: pack W into MFMA fragment order, bf16. (verified)
// ---------------------------------------------------------------------------
__global__ __launch_bounds__(256) void convw_kernel(
    const float* __restrict__ WQ, const float* __restrict__ WK,
    const float* __restrict__ WV, unsigned short* __restrict__ Wpk)
{
  int t = blockIdx.x * 256 + threadIdx.x;     // 0..16383
  int p    = t >> 12;
  int w    = (t >> 10) & 3;
  int kc   = (t >> 6) & 15;
  int lane = t & 63;
  int lr = lane & 15, g = lane >> 4;
  const float* src = (p == 0) ? WQ : ((p == 1) ? WK : WV);
  const float4* s4 = (const float4*)(src + (16 * w + lr) * EMB + kc * 32 + 8 * g);
  float4 a = s4[0], b = s4[1];
  float vv[8] = {a.x, a.y, a.z, a.w, b.x, b.y, b.z, b.w};
  short8 o;
#pragma unroll
  for (int j = 0; j < 8; ++j) {
    unsigned short h = f2bf(vv[j]);
    o[j] = (p == 3) ? (short)f2bf(vv[j] - bf2f(h)) : (short)h;
  }
  *(short8*)(Wpk + (size_t)t * 8) = o;
}

// ---------------------------------------------------------------------------
// Kernel 1: QKV projection. (verified; unchanged)
// ---------------------------------------------------------------------------
#define XST 40   // LDS x row stride in shorts

__global__ __launch_bounds__(256) void proj_kernel(
    const float* __restrict__ x,
    const unsigned short* __restrict__ Wpk,
    unsigned short* __restrict__ Qb,
    unsigned short* __restrict__ Kb,
    unsigned short* __restrict__ VTb)
{
  __shared__ __align__(16) unsigned short Xh[2][32 * XST];
  __shared__ __align__(16) unsigned short Xl[2][32 * XST];

  const int tid  = threadIdx.x;
  const int lane = tid & 63;
  const int w    = tid >> 6;
  const int lr   = lane & 15, g = lane >> 4;
  const long rowBase = (long)blockIdx.x * 32;

  floatx4 accQ[2], accK[2], accV[2];
#pragma unroll
  for (int rt = 0; rt < 2; ++rt) {
    floatx4 z = {0.f, 0.f, 0.f, 0.f};
    accQ[rt] = z; accK[rt] = z; accV[rt] = z;
  }

  const int srow = tid >> 3;
  const int sc   = 4 * (tid & 7);
  const float* xbase = x + (rowBase + srow) * EMB + sc;

  auto stage_write = [&](float4 v, int buf) {
    float vv[4] = {v.x, v.y, v.z, v.w};
    ushort4 hi, lo;
#pragma unroll
    for (int i = 0; i < 4; ++i) {
      unsigned short h = f2bf(vv[i]);
      ((unsigned short*)&hi)[i] = h;
      ((unsigned short*)&lo)[i] = f2bf(vv[i] - bf2f(h));
    }
    *(ushort4*)&Xh[buf][srow * XST + sc] = hi;
    *(ushort4*)&Xl[buf][srow * XST + sc] = lo;
  };

  short8 Wb[2][4];
  {
    const unsigned short* wb_ = Wpk + (size_t)(w * 16) * 512 + lane * 8;
    Wb[0][0] = *(const short8*)(wb_);
    Wb[0][1] = *(const short8*)(wb_ + 32768);
    Wb[0][2] = *(const short8*)(wb_ + 2 * 32768);
    Wb[0][3] = *(const short8*)(wb_ + 3 * 32768);
  }

  float4 xv = *(const float4*)(xbase);
  stage_write(xv, 0);
  float4 xn1 = *(const float4*)(xbase + 32);
  float4 xn2 = *(const float4*)(xbase + 64);
  float4 xn3 = *(const float4*)(xbase + 96);

#pragma unroll 2
  for (int kc = 0; kc < 16; ++kc) {
    if (kc + 1 < 16) {
      const unsigned short* wb_ = Wpk + (size_t)(w * 16 + kc + 1) * 512 + lane * 8;
      Wb[(kc + 1) & 1][0] = *(const short8*)(wb_);
      Wb[(kc + 1) & 1][1] = *(const short8*)(wb_ + 32768);
      Wb[(kc + 1) & 1][2] = *(const short8*)(wb_ + 2 * 32768);
      Wb[(kc + 1) & 1][3] = *(const short8*)(wb_ + 3 * 32768);
    }
    float4 xfut;
    if (kc + 4 < 16) xfut = *(const float4*)(xbase + (kc + 4) * 32);
    __syncthreads();
    const int buf = kc & 1;
#pragma unroll
    for (int rt = 0; rt < 2; ++rt) {
      short8 xh = *(const short8*)&Xh[buf][(16 * rt + lr) * XST + 8 * g];
      short8 xl = *(const short8*)&Xl[buf][(16 * rt + lr) * XST + 8 * g];
      accQ[rt] = __builtin_amdgcn_mfma_f32_16x16x32_bf16(Wb[buf][0], xh, accQ[rt], 0, 0, 0);
      accK[rt] = __builtin_amdgcn_mfma_f32_16x16x32_bf16(Wb[buf][1], xh, accK[rt], 0, 0, 0);
      accV[rt] = __builtin_amdgcn_mfma_f32_16x16x32_bf16(xh, Wb[buf][2], accV[rt], 0, 0, 0);
      accV[rt] = __builtin_amdgcn_mfma_f32_16x16x32_bf16(xl, Wb[buf][2], accV[rt], 0, 0, 0);
      accV[rt] = __builtin_amdgcn_mfma_f32_16x16x32_bf16(xh, Wb[buf][3], accV[rt], 0, 0, 0);
    }
    if (kc + 1 < 16) { stage_write(xn1, (kc + 1) & 1); xn1 = xn2; xn2 = xn3; xn3 = xfut; }
  }

  const int bb  = (int)(rowBase >> 12);
  const int sIn = (int)(rowBase & 4095);
#pragma unroll
  for (int rt = 0; rt < 2; ++rt) {
    {
      long row = rowBase + 16 * rt + lr;
      int  col = 16 * w + 4 * g;
      ushort4 u; u.x = f2bf(accQ[rt][0]); u.y = f2bf(accQ[rt][1]);
      u.z = f2bf(accQ[rt][2]); u.w = f2bf(accQ[rt][3]);
      *(ushort4*)(Qb + row * HD + col) = u;
      ushort4 v; v.x = f2bf(accK[rt][0]); v.y = f2bf(accK[rt][1]);
      v.z = f2bf(accK[rt][2]); v.w = f2bf(accK[rt][3]);
      *(ushort4*)(Kb + row * HD + col) = v;
    }
    {
      long addr = ((long)(bb * 64 + 16 * w + lr)) * SEQ + sIn + 16 * rt + 4 * g;
      ushort4 u; u.x = f2bf(accV[rt][0]); u.y = f2bf(accV[rt][1]);
      u.z = f2bf(accV[rt][2]); u.w = f2bf(accV[rt][3]);
      *(ushort4*)(VTb + addr) = u;
    }
  }
}

// ---------------------------------------------------------------------------
// Kernel 2: flash attention, staged/double-buffered (R1-verified structure),
// OCCUPANCY-RAISED: 32 q/wave (qh<2), 128 q-rows/block, grid 1024
// (128 qb x 8 ks). LDS = 32 KB K/V dbuf + 18.4 KB P = 51.2 KB -> 3
// blocks/CU (12 waves/CU, was 8). Math, staging, softmax, l-as-MFMA and
// the Opart/Lpart layout are identical to the verified R1 kernel.
// ---------------------------------------------------------------------------
#define PST 72   // P row stride in shorts: 144 B (16B-mult)

__global__ __launch_bounds__(256, 3) void flash_kernel(
    const unsigned short* __restrict__ Qb,
    const unsigned short* __restrict__ Kb,
    const unsigned short* __restrict__ VTb,
    unsigned short* __restrict__ Opart,   // fp16 bits [64*8][256][64]
    float* __restrict__ Lpart)            // [64*8][256]
{
  __shared__ __align__(16) unsigned short K0lds[64 * 64];
  __shared__ __align__(16) unsigned short V0lds[64 * 64];
  __shared__ __align__(16) unsigned short K1lds[64 * 64];
  __shared__ __align__(16) unsigned short V1lds[64 * 64];
  __shared__ __align__(16) unsigned short Plds[4][32 * PST];

  const int tid  = threadIdx.x;
  const int lane = tid & 63;
  const int w    = tid >> 6;
  const int lr   = lane & 15, g = lane >> 4;
  const int qb2  = blockIdx.x >> 3;      // 0..127 (128 q rows each)
  const int ks   = blockIdx.x & 7;       // K split (XCD-pinned)
  const int bb   = qb2 >> 5;             // batch
  const long qrow0 = (long)qb2 * 128 + 32 * w;   // wave's global q base row
  const int  kbase = ks * 512;

  short8 qf[2][2];
#pragma unroll
  for (int qh = 0; qh < 2; ++qh)
#pragma unroll
    for (int ec = 0; ec < 2; ++ec)
      qf[qh][ec] = *(const short8*)(Qb + (qrow0 + 16 * qh + lr) * HD + ec * 32 + 8 * g);

  floatx4 accO[2][4];
  floatx4 accL[2];
#pragma unroll
  for (int qh = 0; qh < 2; ++qh) {
    floatx4 z = {0.f, 0.f, 0.f, 0.f};
#pragma unroll
    for (int t = 0; t < 4; ++t) accO[qh][t] = z;
    accL[qh] = z;
  }
  short8 onesf;
#pragma unroll
  for (int j = 0; j < 8; ++j) onesf[j] = (short)0x3F80;

  const float cp = 0.18033688011112042f;   // (1/sqrt(64)) * log2(e)
  const float SH = 2.0f;                   // fixed shift (exp2 domain), exact

#define STAGE(kt_, KL, VL) do {                                               \
    const int k0_ = kbase + (kt_) * 64;                                       \
    _Pragma("unroll")                                                         \
    for (int h_ = 0; h_ < 2; ++h_) {                                          \
      int ci_  = h_ * 256 + tid;                                              \
      int row_ = ci_ >> 3;                                                    \
      int cc_  = (ci_ & 7) ^ (row_ & 7);                                      \
      const unsigned short* gK_ = Kb + ((long)bb * SEQ + k0_ + row_) * HD + cc_ * 8; \
      __builtin_amdgcn_global_load_lds(                                       \
          (const __attribute__((address_space(1))) void*)gK_,                 \
          (__attribute__((address_space(3))) void*)((KL) + ci_ * 8), 16, 0, 0); \
      const unsigned short* gV_ = VTb + ((long)bb * HD + row_) * SEQ + k0_ + cc_ * 8; \
      __builtin_amdgcn_global_load_lds(                                       \
          (const __attribute__((address_space(1))) void*)gV_,                 \
          (__attribute__((address_space(3))) void*)((VL) + ci_ * 8), 16, 0, 0); \
    }                                                                         \
  } while (0)

#define COMPUTE(KL, VL) do {                                                  \
    short8 kf[2][4];                                                          \
    _Pragma("unroll")                                                         \
    for (int ec = 0; ec < 2; ++ec)                                            \
      _Pragma("unroll")                                                       \
      for (int t = 0; t < 4; ++t) {                                           \
        int key  = 16 * t + lr;                                               \
        int slot = key * 8 + ((4 * ec + g) ^ (key & 7));                      \
        kf[ec][t] = *(const short8*)((KL) + slot * 8);                        \
      }                                                                       \
    _Pragma("unroll")                                                         \
    for (int qh = 0; qh < 2; ++qh) {                                          \
      floatx4 s_[4];                                                          \
      _Pragma("unroll")                                                       \
      for (int t = 0; t < 4; ++t) { floatx4 z = {0.f,0.f,0.f,0.f}; s_[t] = z; } \
      _Pragma("unroll")                                                       \
      for (int ec = 0; ec < 2; ++ec)                                          \
        _Pragma("unroll")                                                     \
        for (int t = 0; t < 4; ++t)                                           \
          s_[t] = __builtin_amdgcn_mfma_f32_16x16x32_bf16(kf[ec][t], qf[qh][ec], s_[t], 0, 0, 0); \
      unsigned short* prow = &Plds[w][(16 * qh + lr) * PST];                  \
      _Pragma("unroll")                                                       \
      for (int t = 0; t < 4; ++t) {                                           \
        float p0 = __builtin_amdgcn_exp2f(__builtin_fmaf(s_[t][0], cp, -SH)); \
        float p1 = __builtin_amdgcn_exp2f(__builtin_fmaf(s_[t][1], cp, -SH)); \
        float p2 = __builtin_amdgcn_exp2f(__builtin_fmaf(s_[t][2], cp, -SH)); \
        float p3 = __builtin_amdgcn_exp2f(__builtin_fmaf(s_[t][3], cp, -SH)); \
        uint2 u;                                                              \
        u.x = pack_hi16(p0, p1);                                              \
        u.y = pack_hi16(p2, p3);                                              \
        *(uint2*)(prow + 16 * t + 4 * g) = u;                                 \
      }                                                                       \
    }                                                                         \
    short8 vf[2][4];                                                          \
    _Pragma("unroll")                                                         \
    for (int c = 0; c < 2; ++c)                                               \
      _Pragma("unroll")                                                       \
      for (int t = 0; t < 4; ++t) {                                           \
        int d    = 16 * t + lr;                                               \
        int slot = d * 8 + ((4 * c + g) ^ (d & 7));                           \
        vf[c][t] = *(const short8*)((VL) + slot * 8);                         \
      }                                                                       \
    _Pragma("unroll")                                                         \
    for (int qh = 0; qh < 2; ++qh)                                            \
      _Pragma("unroll")                                                       \
      for (int c = 0; c < 2; ++c) {                                           \
        short8 pf = *(const short8*)(&Plds[w][(16 * qh + lr) * PST + 32 * c + 8 * g]); \
        _Pragma("unroll")                                                     \
        for (int t = 0; t < 4; ++t)                                           \
          accO[qh][t] = __builtin_amdgcn_mfma_f32_16x16x32_bf16(vf[c][t], pf, accO[qh][t], 0, 0, 0); \
        accL[qh] = __builtin_amdgcn_mfma_f32_16x16x32_bf16(onesf, pf, accL[qh], 0, 0, 0); \
      }                                                                       \
  } while (0)

  STAGE(0, K0lds, V0lds);
  for (int kt = 0; kt < 8; kt += 2) {
    __syncthreads();                       // drains tile kt loads (buf0)
    STAGE(kt + 1, K1lds, V1lds);           // prefetch next into buf1
    COMPUTE(K0lds, V0lds);
    __syncthreads();                       // drains tile kt+1 loads (buf1)
    if (kt + 2 < 8) STAGE(kt + 2, K0lds, V0lds);
    COMPUTE(K1lds, V1lds);
  }
#undef STAGE
#undef COMPUTE

  // epilogue: store fp16 O partials + fp32 l (layout identical to R1:
  // Opart[qb(0..63)][ks][qi(0..255)][d]; qb = qb2>>1, qi folds in qb2&1)
  const int qbOld = qb2 >> 1;
  unsigned short* obase = Opart + (size_t)(qbOld * 8 + ks) * 256 * HD;
#pragma unroll
  for (int qh = 0; qh < 2; ++qh) {
    int qlocal = (qb2 & 1) * 128 + 32 * w + 16 * qh + lr;
#pragma unroll
    for (int t = 0; t < 4; ++t) {
      uint2 u;
      u.x = pack_f16(accO[qh][t][0], accO[qh][t][1]);
      u.y = pack_f16(accO[qh][t][2], accO[qh][t][3]);
      *(uint2*)(obase + qlocal * HD + 16 * t + 4 * g) = u;
    }
    if (g == 0) Lpart[(qbOld * 8 + ks) * 256 + qlocal] = accL[qh][0];
  }
}

// ---------------------------------------------------------------------------
// Kernel 3: combine split-K partials. (verified; unchanged)
// ---------------------------------------------------------------------------
__global__ __launch_bounds__(256) void combine_kernel(
    const unsigned short* __restrict__ Opart, const float* __restrict__ Lpart,
    float* __restrict__ out)
{
  int t   = blockIdx.x * 256 + threadIdx.x;    // 0..262143
  int row = t >> 4;
  int d0  = (t & 15) * 4;
  int qb = row >> 8, qi = row & 255;
  float4 acc = {0.f, 0.f, 0.f, 0.f};
  float lt = 0.0f;
#pragma unroll
  for (int ks = 0; ks < 8; ++ks) {
    const unsigned short* p = Opart + ((size_t)(qb * 8 + ks) * 256 + qi) * HD + d0;
    ushort4 v = *(const ushort4*)p;
    acc.x += f16_to_f32(v.x);
    acc.y += f16_to_f32(v.y);
    acc.z += f16_to_f32(v.z);
    acc.w += f16_to_f32(v.w);
    lt += Lpart[(qb * 8 + ks) * 256 + qi];
  }
  float inv = 1.0f / lt;
  float4 o = {acc.x * inv, acc.y * inv, acc.z * inv, acc.w * inv};
  *(float4*)(out + (size_t)row * HD + d0) = o;
}

extern "C" void kernel_launch(void* const* d_in, const int* in_sizes, int n_in,
                              void* d_out, int out_size, void* d_ws, size_t ws_size,
                              hipStream_t stream) {
  const float* x  = (const float*)d_in[0];
  const float* WQ = (const float*)d_in[1];
  const float* WK = (const float*)d_in[2];
  const float* WV = (const float*)d_in[3];

  unsigned short* Qb  = (unsigned short*)d_ws;                  // [16384][64] bf16
  unsigned short* Kb  = Qb  + (size_t)BATCH * SEQ * HD;         // [16384][64] bf16
  unsigned short* VTb = Kb  + (size_t)BATCH * SEQ * HD;         // [4][64][4096] bf16
  unsigned short* Wpk = VTb + (size_t)BATCH * SEQ * HD;         // 262144 shorts
  unsigned short* Opart = Wpk + 262144;                         // fp16 [512][256][64]
  float* Lpart = (float*)(Opart + (size_t)512 * 256 * HD);      // [512][256] f32

  convw_kernel<<<64, 256, 0, stream>>>(WQ, WK, WV, Wpk);
  proj_kernel<<<(BATCH * SEQ) / 32, 256, 0, stream>>>(x, Wpk, Qb, Kb, VTb);
  flash_kernel<<<1024, 256, 0, stream>>>(Qb, Kb, VTb, Opart, Lpart);
  combine_kernel<<<1024, 256, 0, stream>>>(Opart, Lpart, (float*)d_out);
}